// Round 1
// baseline (3752.771 us; speedup 1.0000x reference)
//
#include <hip/hip_runtime.h>

// Graph TransformerConv x2 + MLP head, fp32 baseline.
// N=50000 nodes, E=800000 edges, F_NODE=128, F_EDGE=32, H=4, C1=32, C2=16.

constexpr int NN = 50000;
constexpr int NE = 800000;

// ---- order-preserving float<->uint encoding for atomicMax on floats ----
__device__ __forceinline__ unsigned encodeF(float f) {
  unsigned u = __float_as_uint(f);
  return (u & 0x80000000u) ? ~u : (u | 0x80000000u);
}
__device__ __forceinline__ float decodeF(unsigned u) {
  return (u & 0x80000000u) ? __uint_as_float(u & 0x7fffffffu)
                           : __uint_as_float(~u);
}

__device__ __forceinline__ void atomAddF(float* p, float v) {
  unsafeAtomicAdd(p, v);  // HW global_atomic_add_f32
}

// ---- generic small GEMM: C[n,M] = A[n,K] @ W[K,M] + b ----
template <int K, int M>
__global__ __launch_bounds__(256) void gemm_bias(
    const float* __restrict__ A, const float* __restrict__ W,
    const float* __restrict__ b, float* __restrict__ C, int n) {
  constexpr int RB = 64;
  constexpr int RSTEP = 256 / M;
  __shared__ float As[RB][K];
  const int bi = blockIdx.x * RB;
  for (int idx = threadIdx.x; idx < RB * K; idx += 256) {
    int r = idx / K, c = idx - r * K;
    int gr = bi + r;
    As[r][c] = (gr < n) ? A[(size_t)gr * K + c] : 0.f;
  }
  __syncthreads();
  const int col = threadIdx.x % M;
  const int r0 = threadIdx.x / M;
  const float bias = b[col];
  for (int rbase = r0; rbase < RB; rbase += RSTEP * 4) {
    float a0 = bias, a1 = bias, a2 = bias, a3 = bias;
#pragma unroll 8
    for (int kk = 0; kk < K; ++kk) {
      float w = W[kk * M + col];
      a0 = fmaf(As[rbase][kk], w, a0);
      a1 = fmaf(As[rbase + RSTEP][kk], w, a1);
      a2 = fmaf(As[rbase + 2 * RSTEP][kk], w, a2);
      a3 = fmaf(As[rbase + 3 * RSTEP][kk], w, a3);
    }
    if (bi + rbase < n)              C[(size_t)(bi + rbase) * M + col] = a0;
    if (bi + rbase + RSTEP < n)      C[(size_t)(bi + rbase + RSTEP) * M + col] = a1;
    if (bi + rbase + 2 * RSTEP < n)  C[(size_t)(bi + rbase + 2 * RSTEP) * M + col] = a2;
    if (bi + rbase + 3 * RSTEP < n)  C[(size_t)(bi + rbase + 3 * RSTEP) * M + col] = a3;
  }
}

// ---- per-edge logits: wave per edge; HC = H*C channels; C per head ----
template <int HC, int C>
__global__ __launch_bounds__(256) void edge_logits_k(
    const float* __restrict__ q, const float* __restrict__ k,
    const float* __restrict__ ea, const float* __restrict__ We,
    const int* __restrict__ src, const int* __restrict__ dst,
    float* __restrict__ logits, unsigned* __restrict__ mEnc, int nE) {
  const int wid = (blockIdx.x * 256 + threadIdx.x) >> 6;
  const int lane = threadIdx.x & 63;
  if (wid >= nE) return;
  const int s = src[wid], d = dst[wid];
  constexpr int CPL = HC / 64;     // channels per lane (2 conv1, 1 conv2)
  constexpr int LPH = C / CPL;     // lanes per head (16 both convs)
  const float* eaP = ea + (size_t)wid * 32;
  float dot = 0.f;
#pragma unroll
  for (int j = 0; j < CPL; ++j) {
    const int ch = lane * CPL + j;
    float e = 0.f;
#pragma unroll
    for (int f = 0; f < 32; ++f) e = fmaf(eaP[f], We[f * HC + ch], e);
    dot = fmaf(q[(size_t)d * HC + ch], k[(size_t)s * HC + ch] + e, dot);
  }
#pragma unroll
  for (int off = 1; off < LPH; off <<= 1) dot += __shfl_xor(dot, off);
  if ((lane & (LPH - 1)) == 0) {
    const int h = lane / LPH;
    const float logit = dot * rsqrtf((float)C);
    logits[(size_t)wid * 4 + h] = logit;
    atomicMax(&mEnc[(size_t)d * 4 + h], encodeF(logit));
  }
}

// ---- per-edge accumulate: agg[dst] += p * (v[src]+e); s[dst] += p ----
template <int HC, int C>
__global__ __launch_bounds__(256) void edge_accum_k(
    const float* __restrict__ v, const float* __restrict__ ea,
    const float* __restrict__ We, const int* __restrict__ src,
    const int* __restrict__ dst, const float* __restrict__ logits,
    const unsigned* __restrict__ mEnc, float* __restrict__ sArr,
    float* __restrict__ agg, int nE) {
  const int wid = (blockIdx.x * 256 + threadIdx.x) >> 6;
  const int lane = threadIdx.x & 63;
  if (wid >= nE) return;
  const int s = src[wid], d = dst[wid];
  constexpr int CPL = HC / 64;
  constexpr int LPH = C / CPL;
  const int h = (lane * CPL) / C;
  const float m = decodeF(mEnc[(size_t)d * 4 + h]);
  const float p = expf(logits[(size_t)wid * 4 + h] - m);
  if ((lane & (LPH - 1)) == 0) atomAddF(&sArr[(size_t)d * 4 + h], p);
  const float* eaP = ea + (size_t)wid * 32;
#pragma unroll
  for (int j = 0; j < CPL; ++j) {
    const int ch = lane * CPL + j;
    float e = 0.f;
#pragma unroll
    for (int f = 0; f < 32; ++f) e = fmaf(eaP[f], We[f * HC + ch], e);
    atomAddF(&agg[(size_t)d * HC + ch], p * (v[(size_t)s * HC + ch] + e));
  }
}

// ---- conv1 epilogue: h1 = relu(mean_h(agg/s) + skip) ----
__global__ __launch_bounds__(256) void finish1_k(
    const float* __restrict__ agg, const float* __restrict__ sArr,
    const float* __restrict__ skip, float* __restrict__ h1, int n) {
  const int idx = blockIdx.x * 256 + threadIdx.x;
  if (idx >= n * 32) return;
  const int i = idx >> 5, c = idx & 31;
  float acc = 0.f;
#pragma unroll
  for (int h = 0; h < 4; ++h) {
    float sv = sArr[(size_t)i * 4 + h];
    if (sv > 0.f) acc += agg[(size_t)i * 128 + h * 32 + c] / sv;
  }
  h1[idx] = fmaxf(acc * 0.25f + skip[(size_t)i * 32 + c], 0.f);
}

// ---- conv2 epilogue fused with MLP head: out = relu(relu(h2)@W3+b3)@W4+b4 ----
__global__ __launch_bounds__(256) void finish2_head_k(
    const float* __restrict__ agg, const float* __restrict__ sArr,
    const float* __restrict__ skip, const float* __restrict__ W3,
    const float* __restrict__ b3, const float* __restrict__ W4,
    const float* __restrict__ b4, float* __restrict__ out, int n) {
  const int gtid = blockIdx.x * 256 + threadIdx.x;
  const int node = gtid >> 5;        // half-wave (32 lanes) per node
  const int l = gtid & 31;
  if (node >= n) return;
  float h2 = 0.f;
  if (l < 16) {
    float acc = 0.f;
#pragma unroll
    for (int h = 0; h < 4; ++h) {
      float sv = sArr[(size_t)node * 4 + h];
      if (sv > 0.f) acc += agg[(size_t)node * 64 + h * 16 + l] / sv;
    }
    h2 = fmaxf(acc * 0.25f + skip[(size_t)node * 16 + l], 0.f);
  }
  float t = b3[l];
#pragma unroll
  for (int c = 0; c < 16; ++c) {
    float hv = __shfl(h2, c, 32);
    t = fmaf(hv, W3[c * 32 + l], t);
  }
  t = fmaxf(t, 0.f);
  float p0 = t * W4[l * 2 + 0];
  float p1 = t * W4[l * 2 + 1];
#pragma unroll
  for (int off = 1; off < 32; off <<= 1) {
    p0 += __shfl_xor(p0, off, 32);
    p1 += __shfl_xor(p1, off, 32);
  }
  if (l == 0) {
    out[(size_t)node * 2 + 0] = p0 + b4[0];
    out[(size_t)node * 2 + 1] = p1 + b4[1];
  }
}

extern "C" void kernel_launch(void* const* d_in, const int* in_sizes, int n_in,
                              void* d_out, int out_size, void* d_ws, size_t ws_size,
                              hipStream_t stream) {
  const float* x   = (const float*)d_in[0];
  const int*   ei  = (const int*)d_in[1];
  const float* ea  = (const float*)d_in[2];
  const float* Wq1 = (const float*)d_in[3];  const float* bq1 = (const float*)d_in[4];
  const float* Wk1 = (const float*)d_in[5];  const float* bk1 = (const float*)d_in[6];
  const float* Wv1 = (const float*)d_in[7];  const float* bv1 = (const float*)d_in[8];
  const float* We1 = (const float*)d_in[9];
  const float* Ws1 = (const float*)d_in[10]; const float* bs1 = (const float*)d_in[11];
  const float* Wq2 = (const float*)d_in[12]; const float* bq2 = (const float*)d_in[13];
  const float* Wk2 = (const float*)d_in[14]; const float* bk2 = (const float*)d_in[15];
  const float* Wv2 = (const float*)d_in[16]; const float* bv2 = (const float*)d_in[17];
  const float* We2 = (const float*)d_in[18];
  const float* Ws2 = (const float*)d_in[19]; const float* bs2 = (const float*)d_in[20];
  const float* W3  = (const float*)d_in[21]; const float* b3  = (const float*)d_in[22];
  const float* W4  = (const float*)d_in[23]; const float* b4  = (const float*)d_in[24];
  const int* src = ei;
  const int* dst = ei + NE;

  // workspace layout (floats), with aliasing:
  //   q[N*128] | kagg[N*128] (k then agg) | v[N*128] | skip[N*32]
  //   | mEnc[N*4] | s[N*4] | logits[E*4] (later h1[N*32])
  float* wsf   = (float*)d_ws;
  float* q     = wsf;
  float* kagg  = q + (size_t)NN * 128;
  float* v     = kagg + (size_t)NN * 128;
  float* skip  = v + (size_t)NN * 128;
  unsigned* mEnc = (unsigned*)(skip + (size_t)NN * 32);
  float* sArr  = (float*)mEnc + (size_t)NN * 4;
  float* logits = sArr + (size_t)NN * 4;
  float* h1    = logits;  // alias: h1 written after logits is dead

  const int gemmGrid = (NN + 63) / 64;
  const int edgeGrid = (NE + 3) / 4;
  const int nodeGrid = (NN * 32 + 255) / 256;

  // ---------- conv1 ----------
  hipMemsetAsync(mEnc, 0, (size_t)NN * 8 * sizeof(float), stream);  // m sentinel + s
  gemm_bias<128,128><<<gemmGrid,256,0,stream>>>(x, Wq1, bq1, q, NN);
  gemm_bias<128,128><<<gemmGrid,256,0,stream>>>(x, Wk1, bk1, kagg, NN);
  gemm_bias<128,128><<<gemmGrid,256,0,stream>>>(x, Wv1, bv1, v, NN);
  gemm_bias<128,32><<<gemmGrid,256,0,stream>>>(x, Ws1, bs1, skip, NN);
  edge_logits_k<128,32><<<edgeGrid,256,0,stream>>>(q, kagg, ea, We1, src, dst, logits, mEnc, NE);
  hipMemsetAsync(kagg, 0, (size_t)NN * 128 * sizeof(float), stream); // k dead -> agg
  edge_accum_k<128,32><<<edgeGrid,256,0,stream>>>(v, ea, We1, src, dst, logits, mEnc, sArr, kagg, NE);
  finish1_k<<<nodeGrid,256,0,stream>>>(kagg, sArr, skip, h1, NN);

  // ---------- conv2 ----------
  hipMemsetAsync(mEnc, 0, (size_t)NN * 8 * sizeof(float), stream);
  gemm_bias<32,64><<<gemmGrid,256,0,stream>>>(h1, Wq2, bq2, q, NN);
  gemm_bias<32,64><<<gemmGrid,256,0,stream>>>(h1, Wk2, bk2, kagg, NN);
  gemm_bias<32,64><<<gemmGrid,256,0,stream>>>(h1, Wv2, bv2, v, NN);
  gemm_bias<32,16><<<gemmGrid,256,0,stream>>>(h1, Ws2, bs2, skip, NN);
  edge_logits_k<64,16><<<edgeGrid,256,0,stream>>>(q, kagg, ea, We2, src, dst, logits, mEnc, NE);
  hipMemsetAsync(kagg, 0, (size_t)NN * 64 * sizeof(float), stream);
  edge_accum_k<64,16><<<edgeGrid,256,0,stream>>>(v, ea, We2, src, dst, logits, mEnc, sArr, kagg, NE);
  finish2_head_k<<<nodeGrid,256,0,stream>>>(kagg, sArr, skip, W3, b3, W4, b4, (float*)d_out, NN);
}

// Round 3
// 1061.738 us; speedup vs baseline: 3.5346x; 3.5346x over previous
//
#include <hip/hip_runtime.h>

// Graph TransformerConv x2 + MLP head. CSR-based, atomic-free edge phase.
// N=50000 nodes, E=800000 edges, F_NODE=128, F_EDGE=32, H=4, C1=32, C2=16.

constexpr int NN = 50000;
constexpr int NE = 800000;

// ---- generic small GEMM: C[n,M] = A[n,K] @ W[K,M] + b ----
template <int K, int M>
__global__ __launch_bounds__(256) void gemm_bias(
    const float* __restrict__ A, const float* __restrict__ W,
    const float* __restrict__ b, float* __restrict__ C, int n) {
  constexpr int RB = 64;
  constexpr int RSTEP = 256 / M;
  __shared__ float As[RB][K];
  const int bi = blockIdx.x * RB;
  for (int idx = threadIdx.x; idx < RB * K; idx += 256) {
    int r = idx / K, c = idx - r * K;
    int gr = bi + r;
    As[r][c] = (gr < n) ? A[(size_t)gr * K + c] : 0.f;
  }
  __syncthreads();
  const int col = threadIdx.x % M;
  const int r0 = threadIdx.x / M;
  const float bias = b[col];
  for (int rbase = r0; rbase < RB; rbase += RSTEP * 4) {
    float a0 = bias, a1 = bias, a2 = bias, a3 = bias;
#pragma unroll 8
    for (int kk = 0; kk < K; ++kk) {
      float w = W[kk * M + col];
      a0 = fmaf(As[rbase][kk], w, a0);
      a1 = fmaf(As[rbase + RSTEP][kk], w, a1);
      a2 = fmaf(As[rbase + 2 * RSTEP][kk], w, a2);
      a3 = fmaf(As[rbase + 3 * RSTEP][kk], w, a3);
    }
    if (bi + rbase < n)              C[(size_t)(bi + rbase) * M + col] = a0;
    if (bi + rbase + RSTEP < n)      C[(size_t)(bi + rbase + RSTEP) * M + col] = a1;
    if (bi + rbase + 2 * RSTEP < n)  C[(size_t)(bi + rbase + 2 * RSTEP) * M + col] = a2;
    if (bi + rbase + 3 * RSTEP < n)  C[(size_t)(bi + rbase + 3 * RSTEP) * M + col] = a3;
  }
}

// ---- CSR build ----
__global__ __launch_bounds__(256) void hist_k(const int* __restrict__ dst,
                                              int* __restrict__ deg, int nE) {
  const int i = blockIdx.x * 256 + threadIdx.x;
  if (i < nE) atomicAdd(&deg[dst[i]], 1);
}

__global__ __launch_bounds__(1024) void scan_k(const int* __restrict__ deg,
                                               int* __restrict__ rowptr,
                                               int* __restrict__ cursor, int n) {
  __shared__ int part[1024];
  const int t = threadIdx.x;
  const int chunk = (n + 1023) / 1024;
  const int lo = t * chunk;
  const int hi = min(lo + chunk, n);
  int s = 0;
  for (int i = lo; i < hi; ++i) s += deg[i];
  part[t] = s;
  __syncthreads();
  for (int off = 1; off < 1024; off <<= 1) {
    int tmp = (t >= off) ? part[t - off] : 0;
    __syncthreads();
    part[t] += tmp;
    __syncthreads();
  }
  int base = (t == 0) ? 0 : part[t - 1];
  for (int i = lo; i < hi; ++i) {
    rowptr[i] = base;
    cursor[i] = base;
    base += deg[i];
  }
  if (t == 1023) rowptr[n] = part[1023];
}

__global__ __launch_bounds__(256) void scatter_k(
    const int* __restrict__ src, const int* __restrict__ dst,
    int* __restrict__ cursor, int* __restrict__ csr_src,
    int* __restrict__ csr_eid, int nE) {
  const int i = blockIdx.x * 256 + threadIdx.x;
  if (i < nE) {
    const int d = dst[i];
    const int pos = atomicAdd(&cursor[d], 1);
    csr_src[pos] = src[i];
    csr_eid[pos] = i;
  }
}

// ---- fused dst-centric attention aggregate (one wave per node) ----
// HC = H*C total channels; C per head. CPL = HC/64 channels per lane.
// Online softmax per 16-lane head group, all in registers. FINAL fuses MLP head.
template <int HC, int C, bool FINAL>
__global__ __launch_bounds__(256) void tconv_agg_k(
    const float* __restrict__ q, const float* __restrict__ k,
    const float* __restrict__ v, const float* __restrict__ ea,
    const float* __restrict__ We, const int* __restrict__ rowptr,
    const int* __restrict__ csr_src, const int* __restrict__ csr_eid,
    const float* __restrict__ skip, const float* __restrict__ W3,
    const float* __restrict__ b3, const float* __restrict__ W4,
    const float* __restrict__ b4, float* __restrict__ out, int n) {
  const int d = (blockIdx.x * 256 + threadIdx.x) >> 6;
  const int lane = threadIdx.x & 63;
  if (d >= n) return;
  constexpr int CPL = HC / 64;      // 2 for conv1, 1 for conv2
  constexpr int LPH = C / CPL;      // 16 lanes per head for both
  const int ch0 = lane * CPL;

  // hoist We columns for this lane's channels into registers
  float we0[32], we1[32];
#pragma unroll
  for (int f = 0; f < 32; ++f) {
    if constexpr (CPL == 2) {
      const float2 w = *(const float2*)&We[f * HC + ch0];
      we0[f] = w.x; we1[f] = w.y;
    } else {
      we0[f] = We[f * HC + ch0]; we1[f] = 0.f;
    }
  }
  const float q0 = q[(size_t)d * HC + ch0];
  const float q1 = (CPL == 2) ? q[(size_t)d * HC + ch0 + 1] : 0.f;
  const float inv = rsqrtf((float)C);

  float m = -INFINITY, sden = 0.f, acc0 = 0.f, acc1 = 0.f;
  const int p0i = rowptr[d], p1i = rowptr[d + 1];
  for (int pos = p0i; pos < p1i; ++pos) {
    const int sn = __builtin_amdgcn_readfirstlane(csr_src[pos]);
    const int eid = __builtin_amdgcn_readfirstlane(csr_eid[pos]);
    const float* __restrict__ eaP = ea + (size_t)eid * 32;
    float ee0 = 0.f, ee1 = 0.f;
#pragma unroll
    for (int f = 0; f < 32; ++f) {
      const float eav = eaP[f];
      ee0 = fmaf(eav, we0[f], ee0);
      if constexpr (CPL == 2) ee1 = fmaf(eav, we1[f], ee1);
    }
    const float* __restrict__ kP = k + (size_t)sn * HC + ch0;
    const float* __restrict__ vP = v + (size_t)sn * HC + ch0;
    float dot = q0 * (kP[0] + ee0);
    if constexpr (CPL == 2) dot = fmaf(q1, kP[1] + ee1, dot);
#pragma unroll
    for (int off = 1; off < LPH; off <<= 1) dot += __shfl_xor(dot, off);
    const float logit = dot * inv;
    const float newm = fmaxf(m, logit);
    const float scale = __expf(m - newm);   // exp(-inf)=0 on first edge
    const float p = __expf(logit - newm);
    m = newm;
    sden = sden * scale + p;
    acc0 = acc0 * scale + p * (vP[0] + ee0);
    if constexpr (CPL == 2) acc1 = acc1 * scale + p * (vP[1] + ee1);
  }
  const float rs = (sden > 0.f) ? 1.f / sden : 0.f;
  acc0 *= rs;
  if constexpr (CPL == 2) acc1 *= rs;
  // head-mean: sum across the 4 head groups (lanes l, l^16, l^32, l^48)
  acc0 += __shfl_xor(acc0, 16); acc0 += __shfl_xor(acc0, 32);
  if constexpr (CPL == 2) { acc1 += __shfl_xor(acc1, 16); acc1 += __shfl_xor(acc1, 32); }

  if constexpr (!FINAL) {
    // h1 = relu(mean + skip); lane l<16 owns channels 2l, 2l+1
    if (lane < 16) {
      const int c0 = 2 * lane;
      out[(size_t)d * 32 + c0]     = fmaxf(acc0 * 0.25f + skip[(size_t)d * 32 + c0], 0.f);
      out[(size_t)d * 32 + c0 + 1] = fmaxf(acc1 * 0.25f + skip[(size_t)d * 32 + c0 + 1], 0.f);
    }
  } else {
    // h2 = relu(mean + skip) for c = lane&15 (replicated across 4 groups)
    const int c = lane & 15;
    const float h2 = fmaxf(acc0 * 0.25f + skip[(size_t)d * 16 + c], 0.f);
    const int j = lane & 31;
    float t3 = b3[j];
#pragma unroll
    for (int cc = 0; cc < 16; ++cc)
      t3 = fmaf(__shfl(h2, cc), W3[cc * 32 + j], t3);
    t3 = fmaxf(t3, 0.f);
    float o0 = t3 * W4[j * 2 + 0];
    float o1 = t3 * W4[j * 2 + 1];
#pragma unroll
    for (int off = 1; off < 32; off <<= 1) {
      o0 += __shfl_xor(o0, off);
      o1 += __shfl_xor(o1, off);
    }
    if (lane == 0) {
      out[(size_t)d * 2 + 0] = o0 + b4[0];
      out[(size_t)d * 2 + 1] = o1 + b4[1];
    }
  }
}

extern "C" void kernel_launch(void* const* d_in, const int* in_sizes, int n_in,
                              void* d_out, int out_size, void* d_ws, size_t ws_size,
                              hipStream_t stream) {
  const float* x   = (const float*)d_in[0];
  const int*   ei  = (const int*)d_in[1];
  const float* ea  = (const float*)d_in[2];
  const float* Wq1 = (const float*)d_in[3];  const float* bq1 = (const float*)d_in[4];
  const float* Wk1 = (const float*)d_in[5];  const float* bk1 = (const float*)d_in[6];
  const float* Wv1 = (const float*)d_in[7];  const float* bv1 = (const float*)d_in[8];
  const float* We1 = (const float*)d_in[9];
  const float* Ws1 = (const float*)d_in[10]; const float* bs1 = (const float*)d_in[11];
  const float* Wq2 = (const float*)d_in[12]; const float* bq2 = (const float*)d_in[13];
  const float* Wk2 = (const float*)d_in[14]; const float* bk2 = (const float*)d_in[15];
  const float* Wv2 = (const float*)d_in[16]; const float* bv2 = (const float*)d_in[17];
  const float* We2 = (const float*)d_in[18];
  const float* Ws2 = (const float*)d_in[19]; const float* bs2 = (const float*)d_in[20];
  const float* W3  = (const float*)d_in[21]; const float* b3  = (const float*)d_in[22];
  const float* W4  = (const float*)d_in[23]; const float* b4  = (const float*)d_in[24];
  const int* src = ei;
  const int* dst = ei + NE;

  // workspace layout
  float* wsf    = (float*)d_ws;
  float* q      = wsf;                       // N*128
  float* kbuf   = q + (size_t)NN * 128;      // N*128
  float* vbuf   = kbuf + (size_t)NN * 128;   // N*128
  float* skip   = vbuf + (size_t)NN * 128;   // N*32
  float* h1     = skip + (size_t)NN * 32;    // N*32
  int* deg      = (int*)(h1 + (size_t)NN * 32);  // N
  int* rowptr   = deg + NN;                  // N+1
  int* cursor   = rowptr + NN + 1;           // N
  int* csr_src  = cursor + NN;               // E
  int* csr_eid  = csr_src + NE;              // E

  const int gemmGrid = (NN + 63) / 64;
  const int edgeGrid = (NE + 255) / 256;
  const int aggGrid  = (NN + 3) / 4;         // one wave per node

  // ---------- CSR build (by dst) ----------
  hipMemsetAsync(deg, 0, (size_t)NN * sizeof(int), stream);
  hist_k<<<edgeGrid, 256, 0, stream>>>(dst, deg, NE);
  scan_k<<<1, 1024, 0, stream>>>(deg, rowptr, cursor, NN);
  scatter_k<<<edgeGrid, 256, 0, stream>>>(src, dst, cursor, csr_src, csr_eid, NE);

  // ---------- conv1 ----------
  gemm_bias<128,128><<<gemmGrid,256,0,stream>>>(x, Wq1, bq1, q, NN);
  gemm_bias<128,128><<<gemmGrid,256,0,stream>>>(x, Wk1, bk1, kbuf, NN);
  gemm_bias<128,128><<<gemmGrid,256,0,stream>>>(x, Wv1, bv1, vbuf, NN);
  gemm_bias<128,32><<<gemmGrid,256,0,stream>>>(x, Ws1, bs1, skip, NN);
  tconv_agg_k<128,32,false><<<aggGrid,256,0,stream>>>(
      q, kbuf, vbuf, ea, We1, rowptr, csr_src, csr_eid, skip,
      nullptr, nullptr, nullptr, nullptr, h1, NN);

  // ---------- conv2 + fused MLP head ----------
  gemm_bias<32,64><<<gemmGrid,256,0,stream>>>(h1, Wq2, bq2, q, NN);
  gemm_bias<32,64><<<gemmGrid,256,0,stream>>>(h1, Wk2, bk2, kbuf, NN);
  gemm_bias<32,64><<<gemmGrid,256,0,stream>>>(h1, Wv2, bv2, vbuf, NN);
  gemm_bias<32,16><<<gemmGrid,256,0,stream>>>(h1, Ws2, bs2, skip, NN);
  tconv_agg_k<64,16,true><<<aggGrid,256,0,stream>>>(
      q, kbuf, vbuf, ea, We2, rowptr, csr_src, csr_eid, skip,
      W3, b3, W4, b4, (float*)d_out, NN);
}